// Round 2
// baseline (745.040 us; speedup 1.0000x reference)
//
#include <hip/hip_runtime.h>
#include <hip/hip_bf16.h>
#include <stdint.h>

#define NN 50000
#define FF 256
#define HH 128
#define RR 16
#define EE 800000
#define CC 7
#define NB_ 30

typedef __attribute__((ext_vector_type(8))) short short8;
typedef __attribute__((ext_vector_type(4))) float f32x4;

__device__ __forceinline__ float bf2f(unsigned short u){
  union { unsigned int i; float f; } x; x.i = ((unsigned int)u) << 16; return x.f;
}
__device__ __forceinline__ unsigned short f2bf(float f){
  union { unsigned int i; float f; } x; x.f = f;
  unsigned int r = x.i + 0x7fffu + ((x.i >> 16) & 1u);
  return (unsigned short)(r >> 16);
}

// ---------------- bf16 MFMA GEMM: C[M,Ncols] = A[M,K] * Bt[Ncols,K]^T ----------
// A can be split column-wise at kSplit between two sources (for concat inputs).
// 128x128 tile, BK=64, 4 waves (2x2), each wave 64x64 via 16x16x32 MFMA.
template<bool BIAS, bool RELU>
__global__ __launch_bounds__(256) void gemm_bt(
    const unsigned short* __restrict__ A0, int ldA0,
    const unsigned short* __restrict__ A1, int ldA1, int kSplit,
    const unsigned short* __restrict__ Bt,
    unsigned short* __restrict__ Cout, int ldC,
    const float* __restrict__ bias,
    int M, int K)
{
  __shared__ unsigned short Al[128][72];   // +8 pad: conflict-light, 16B-aligned rows
  __shared__ unsigned short Bl[128][72];
  const int tid  = threadIdx.x;
  const int lane = tid & 63;
  const int wid  = tid >> 6;
  const int wr   = wid >> 1, wc = wid & 1;
  const int bm   = blockIdx.x, bn = blockIdx.y;

  f32x4 acc[4][4];
  #pragma unroll
  for (int m=0;m<4;m++)
    #pragma unroll
    for (int n=0;n<4;n++) acc[m][n] = (f32x4){0.f,0.f,0.f,0.f};

  const int nkt = K >> 6;
  for (int kt=0; kt<nkt; ++kt){
    int c0 = kt*64;
    const unsigned short* Asrc = A0; int lda = ldA0;
    if (c0 >= kSplit){ Asrc = A1; lda = ldA1; c0 -= kSplit; }
    #pragma unroll
    for (int p=0;p<4;p++){
      int rt = p*32 + (tid>>3);
      int ce = (tid&7)*8;
      int gr = bm*128 + rt;
      uint4 v = make_uint4(0u,0u,0u,0u);
      if (gr < M) v = *(const uint4*)(Asrc + (size_t)gr*lda + c0 + ce);
      *(uint4*)&Al[rt][ce] = v;
      int gc = bn*128 + rt;
      uint4 vb = *(const uint4*)(Bt + (size_t)gc*K + kt*64 + ce);
      *(uint4*)&Bl[rt][ce] = vb;
    }
    __syncthreads();
    #pragma unroll
    for (int ks=0; ks<2; ++ks){
      short8 a[4], b[4];
      #pragma unroll
      for (int m=0;m<4;m++)
        a[m] = *(const short8*)&Al[wr*64 + m*16 + (lane&15)][ks*32 + (lane>>4)*8];
      #pragma unroll
      for (int n=0;n<4;n++)
        b[n] = *(const short8*)&Bl[wc*64 + n*16 + (lane&15)][ks*32 + (lane>>4)*8];
      #pragma unroll
      for (int m=0;m<4;m++)
        #pragma unroll
        for (int n=0;n<4;n++)
          acc[m][n] = __builtin_amdgcn_mfma_f32_16x16x32_bf16(a[m], b[n], acc[m][n], 0, 0, 0);
    }
    __syncthreads();
  }

  #pragma unroll
  for (int m=0;m<4;m++){
    #pragma unroll
    for (int n=0;n<4;n++){
      #pragma unroll
      for (int j=0;j<4;j++){
        int row = bm*128 + wr*64 + m*16 + ((lane>>4)<<2) + j;
        int col = bn*128 + wc*64 + n*16 + (lane&15);
        if (row < M){
          float v = acc[m][n][j];
          if (BIAS) v += bias[col];
          if (RELU) v = fmaxf(v, 0.f);
          Cout[(size_t)row*ldC + col] = f2bf(v);
        }
      }
    }
  }
}

// ---------------- small prep kernels ----------------
__global__ void k_cvt(const float* __restrict__ in, unsigned short* __restrict__ out, int n4){
  int i = blockIdx.x*256 + threadIdx.x;
  if (i >= n4) return;
  float4 v = ((const float4*)in)[i];
  union { unsigned short u[4]; uint2 q; } t;
  t.u[0]=f2bf(v.x); t.u[1]=f2bf(v.y); t.u[2]=f2bf(v.z); t.u[3]=f2bf(v.w);
  ((uint2*)out)[i] = t.q;
}

// WT[(r*128+o)][i] = sum_b comp[r,b]*basis[b,i,o]  -> [2048,256] bf16 (B^T for GEMM1)
__global__ void k_build_wt(const float* __restrict__ comp, const float* __restrict__ basis,
                           unsigned short* __restrict__ WT){
  int row = blockIdx.x;     // 0..2047  = r*128+o
  int i   = threadIdx.x;    // 0..255
  int r = row >> 7, o = row & 127;
  float s = 0.f;
  #pragma unroll 5
  for (int b=0;b<NB_;b++) s += comp[r*NB_+b]*basis[((size_t)b*FF+i)*HH+o];
  WT[(size_t)row*FF + i] = f2bf(s);
}

// outT[o][k] = k<k0 ? in0[k*128+o] : in1[(k-k0)*128+o]    (bf16 B^T builder)
__global__ void k_transpose_cat(const float* __restrict__ in0, int k0,
                                const float* __restrict__ in1, int k1,
                                unsigned short* __restrict__ outT){
  int K = k0 + k1;
  int idx = blockIdx.x*256 + threadIdx.x;
  if (idx >= 128*K) return;
  int o = idx / K, k = idx % K;
  float v = (k < k0) ? in0[(size_t)k*HH + o] : in1[(size_t)(k-k0)*HH + o];
  outT[idx] = f2bf(v);
}

// ---------------- CSR by dst ----------------
__global__ void k_count(const int* __restrict__ dstv, int* __restrict__ counts){
  int e = blockIdx.x*256 + threadIdx.x;
  if (e >= EE) return;
  atomicAdd(&counts[dstv[e]], 1);
}

__global__ __launch_bounds__(1024) void k_scan(const int* __restrict__ counts, int* __restrict__ row_ptr){
  __shared__ int sm[1024];
  __shared__ int carry;
  int t = threadIdx.x;
  if (t==0) carry = 0;
  __syncthreads();
  for (int base=0; base<NN; base+=1024){
    int v = (base+t < NN) ? counts[base+t] : 0;
    sm[t] = v; __syncthreads();
    for (int off=1; off<1024; off<<=1){
      int x = sm[t];
      int y = (t>=off) ? sm[t-off] : 0;
      __syncthreads();
      sm[t] = x + y;
      __syncthreads();
    }
    int incl = sm[t];
    if (base+t < NN) row_ptr[base+t] = carry + incl - v;
    __syncthreads();
    if (t==1023) carry += sm[1023];
    __syncthreads();
  }
  if (t==0) row_ptr[NN] = EE;
}

__global__ void k_fill(const int* __restrict__ srcv, const int* __restrict__ dstv,
                       const int* __restrict__ etv, const int* __restrict__ row_ptr,
                       int* __restrict__ cursor, int* __restrict__ packed){
  int e = blockIdx.x*256 + threadIdx.x;
  if (e >= EE) return;
  int d = dstv[e];
  int p = atomicAdd(&cursor[d], 1);
  packed[row_ptr[d] + p] = (srcv[e] & 0xffff) | (etv[e] << 16);
}

// ---- RGCN aggregate (mean per (dst,rel)); adds into existing out1_bf (= x@root1+bias1) ----
__global__ __launch_bounds__(256) void k_agg1(const int* __restrict__ row_ptr,
                                              const int* __restrict__ packed,
                                              const unsigned short* __restrict__ xW,
                                              unsigned short* __restrict__ out1_bf){
  int half = threadIdx.x >> 7;
  int col  = threadIdx.x & 127;
  int node = blockIdx.x*2 + half;
  __shared__ int   cnt[2][RR];
  __shared__ float inv[2][RR];
  if (col < RR) cnt[half][col] = 0;
  __syncthreads();
  int b0 = 0, b1 = 0;
  if (node < NN){ b0 = row_ptr[node]; b1 = row_ptr[node+1]; }
  for (int j=b0+col; j<b1; j+=128) atomicAdd(&cnt[half][(packed[j]>>16)&15], 1);
  __syncthreads();
  if (col < RR) inv[half][col] = 1.0f / fmaxf((float)cnt[half][col], 1.0f);
  __syncthreads();
  if (node >= NN) return;
  float acc = 0.f;
  for (int j=b0; j<b1; ++j){
    int p = packed[j];
    int s = p & 0xffff;
    int r = (p >> 16) & 15;
    acc += bf2f(xW[(size_t)s*2048 + r*128 + col]) * inv[half][r];
  }
  size_t o = (size_t)node*128 + col;
  out1_bf[o] = f2bf(acc + bf2f(out1_bf[o]));
}

// ---------------- GraphConv aggregate: agg2[n] = sum_{e: dst=n} out1[src] ----------------
__global__ __launch_bounds__(256) void k_agg2(const int* __restrict__ row_ptr,
                                              const int* __restrict__ packed,
                                              const unsigned short* __restrict__ out1_bf,
                                              unsigned short* __restrict__ agg2_bf){
  int half = threadIdx.x >> 7;
  int col  = threadIdx.x & 127;
  int node = blockIdx.x*2 + half;
  if (node >= NN) return;
  int b0 = row_ptr[node], b1 = row_ptr[node+1];
  float acc = 0.f;
  for (int j=b0; j<b1; ++j){
    int s = packed[j] & 0xffff;
    acc += bf2f(out1_bf[(size_t)s*128 + col]);
  }
  agg2_bf[(size_t)node*128 + col] = f2bf(acc);
}

// ---------------- head: logits + log_softmax ----------------
__global__ __launch_bounds__(256) void k_head(const unsigned short* __restrict__ hidden,
                                              const float* __restrict__ fc_w,
                                              const float* __restrict__ fc_b,
                                              float* __restrict__ out){
  int node = blockIdx.x*4 + (threadIdx.x >> 6);
  int lane = threadIdx.x & 63;
  if (node >= NN) return;
  float h0 = bf2f(hidden[(size_t)node*128 + lane*2]);
  float h1 = bf2f(hidden[(size_t)node*128 + lane*2 + 1]);
  float lg[CC];
  #pragma unroll
  for (int c=0;c<CC;c++){
    float p = h0*fc_w[(lane*2)*CC + c] + h1*fc_w[(lane*2+1)*CC + c];
    #pragma unroll
    for (int off=32; off; off>>=1) p += __shfl_down(p, off, 64);
    lg[c] = p;
  }
  if (lane == 0){
    float l[CC]; float m = -1e30f;
    #pragma unroll
    for (int c=0;c<CC;c++){ l[c] = lg[c] + fc_b[c]; m = fmaxf(m, l[c]); }
    float s = 0.f;
    #pragma unroll
    for (int c=0;c<CC;c++) s += expf(l[c]-m);
    float lse = logf(s);
    #pragma unroll
    for (int c=0;c<CC;c++) out[(size_t)node*CC + c] = l[c] - m - lse;
  }
}

extern "C" void kernel_launch(void* const* d_in, const int* in_sizes, int n_in,
                              void* d_out, int out_size, void* d_ws, size_t ws_size,
                              hipStream_t stream)
{
  const float* x      = (const float*)d_in[0];
  const int*   eidx   = (const int*)d_in[1];
  const int*   etype  = (const int*)d_in[3];
  const float* basis  = (const float*)d_in[8];
  const float* comp   = (const float*)d_in[9];
  const float* root1  = (const float*)d_in[10];
  const float* bias1  = (const float*)d_in[11];
  const float* w_rel  = (const float*)d_in[12];
  const float* w_root = (const float*)d_in[13];
  const float* bias2  = (const float*)d_in[14];
  const float* lin_w  = (const float*)d_in[15];
  const float* lin_b  = (const float*)d_in[16];
  const float* fc_w   = (const float*)d_in[17];
  const float* fc_b   = (const float*)d_in[18];
  const int* srcv = eidx;
  const int* dstv = eidx + EE;

  // workspace layout: TOTAL 248,278,528 B  (fits 256MB decimal and 256MiB pools)
  char* w = (char*)d_ws;
  unsigned short* x_bf    = (unsigned short*)(w + 0);            // 25,600,000
  unsigned short* xW      = (unsigned short*)(w + 25600000);     // 204,800,000 (dead after k_agg1)
  unsigned short* hidden  = (unsigned short*)(w + 25600000);     //   alias xW + 0        (12.8MB)
  unsigned short* out2_bf = (unsigned short*)(w + 25600000 + 12800000);  // alias xW+12.8MB
  unsigned short* agg2_bf = (unsigned short*)(w + 25600000 + 25600000);  // alias xW+25.6MB
  unsigned short* WT      = (unsigned short*)(w + 230400000);    // 1,048,576
  unsigned short* rootT   = (unsigned short*)(w + 231448576);    // 65,536
  unsigned short* W2T     = (unsigned short*)(w + 231514112);    // 65,536
  unsigned short* linT    = (unsigned short*)(w + 231579648);    // 98,304
  unsigned short* out1_bf = (unsigned short*)(w + 231677952);    // 12,800,000
  int*            counts  = (int*)(w + 244477952);               // 200,192
  int*            row_ptr = (int*)(w + 244678144);               // 200,192
  int*            cursor  = (int*)(w + 244878336);               // 200,192
  int*            packed  = (int*)(w + 245078528);               // 3,200,000 -> ends 248,278,528

  hipMemsetAsync(counts, 0, NN*4, stream);
  hipMemsetAsync(cursor, 0, NN*4, stream);

  // prep
  k_cvt<<<12500, 256, 0, stream>>>(x, x_bf, NN*FF/4);
  k_build_wt<<<2048, 256, 0, stream>>>(comp, basis, WT);
  k_transpose_cat<<<128, 256, 0, stream>>>(root1, 256, nullptr, 0, rootT);
  k_transpose_cat<<<128, 256, 0, stream>>>(w_rel, 128, w_root, 128, W2T);
  k_transpose_cat<<<192, 256, 0, stream>>>(lin_w, 384, nullptr, 0, linT);

  // CSR by dst
  k_count<<<3125, 256, 0, stream>>>(dstv, counts);
  k_scan<<<1, 1024, 0, stream>>>(counts, row_ptr);
  k_fill<<<3125, 256, 0, stream>>>(srcv, dstv, etype, row_ptr, cursor, packed);

  // GEMM1: xW = x_bf @ W  -> [N, 2048] bf16
  {
    dim3 g(391, 16);
    gemm_bt<false,false><<<g, 256, 0, stream>>>(
        x_bf, FF, nullptr, 0, 1<<30, WT, xW, 2048, nullptr, NN, FF);
  }
  // root: out1_bf = x_bf @ root1 + bias1  (bf16)
  {
    dim3 g(391, 1);
    gemm_bt<true,false><<<g, 256, 0, stream>>>(
        x_bf, FF, nullptr, 0, 1<<30, rootT, out1_bf, HH, bias1, NN, FF);
  }
  // RGCN aggregate: out1_bf += mean-per-(dst,rel) messages
  k_agg1<<<25000, 256, 0, stream>>>(row_ptr, packed, xW, out1_bf);
  // GraphConv aggregate -> agg2_bf
  k_agg2<<<25000, 256, 0, stream>>>(row_ptr, packed, out1_bf, agg2_bf);
  // GEMM2: out2 = [agg2 | out1] @ [w_rel; w_root] + bias2 -> bf16
  {
    dim3 g(391, 1);
    gemm_bt<true,false><<<g, 256, 0, stream>>>(
        agg2_bf, HH, out1_bf, HH, HH, W2T, out2_bf, HH, bias2, NN, 2*HH);
  }
  // GEMM3: hidden = relu([x | out2] @ lin_w + lin_b) -> bf16
  {
    dim3 g(391, 1);
    gemm_bt<true,true><<<g, 256, 0, stream>>>(
        x_bf, FF, out2_bf, HH, FF, linT, hidden, HH, lin_b, NN, FF+HH);
  }
  // head
  k_head<<<12500, 256, 0, stream>>>(hidden, fc_w, fc_b, (float*)d_out);
}

// Round 4
// 421.472 us; speedup vs baseline: 1.7677x; 1.7677x over previous
//
#include <hip/hip_runtime.h>
#include <hip/hip_bf16.h>
#include <stdint.h>

#define NN 50000
#define FF 256
#define HH 128
#define RR 16
#define EE 800000
#define CC 7
#define NB_ 30

typedef __attribute__((ext_vector_type(8))) short short8;
typedef __attribute__((ext_vector_type(4))) float f32x4;

__device__ __forceinline__ float bf2f(unsigned short u){
  union { unsigned int i; float f; } x; x.i = ((unsigned int)u) << 16; return x.f;
}
__device__ __forceinline__ unsigned short f2bf(float f){
  union { unsigned int i; float f; } x; x.f = f;
  unsigned int r = x.i + 0x7fffu + ((x.i >> 16) & 1u);
  return (unsigned short)(r >> 16);
}

__device__ __forceinline__ void gld16(const unsigned short* g, unsigned short* l){
  __builtin_amdgcn_global_load_lds(
      (const __attribute__((address_space(1))) unsigned int*)g,
      (__attribute__((address_space(3))) unsigned int*)l, 16, 0, 0);
}

// ---------------- bf16 MFMA GEMM: C[M,Ncols] = A[M,K] * Bt[Ncols,K]^T ----------
// m97 structure: 128x128 tile, BK=64, 4 waves, global_load_lds staging, linear LDS.
// A rows may be read up to the 128-aligned boundary: all A sources padded in ws.
template<bool BIAS, bool RELU>
__global__ __launch_bounds__(256) void gemm_bt(
    const unsigned short* __restrict__ A0, int ldA0,
    const unsigned short* __restrict__ A1, int ldA1, int kSplit,
    const unsigned short* __restrict__ Bt,
    unsigned short* __restrict__ Cout, int ldC,
    const float* __restrict__ bias,
    int M, int K)
{
  __shared__ unsigned short Al[128*64];
  __shared__ unsigned short Bl[128*64];
  const int tid  = threadIdx.x;
  const int lane = tid & 63;
  const int wid  = tid >> 6;
  const int wr   = wid >> 1, wc = wid & 1;
  const int bm   = blockIdx.x, bn = blockIdx.y;

  f32x4 acc[4][4];
  #pragma unroll
  for (int m=0;m<4;m++)
    #pragma unroll
    for (int n=0;n<4;n++) acc[m][n] = (f32x4){0.f,0.f,0.f,0.f};

  const int nkt = K >> 6;
  for (int kt=0; kt<nkt; ++kt){
    int c0 = kt*64;
    const unsigned short* Asrc = A0; int lda = ldA0;
    if (c0 >= kSplit){ Asrc = A1; lda = ldA1; c0 -= kSplit; }
    // stage: each wave loads 32 rows of A and 32 rows of B (4 x 1KB each)
    const unsigned short* arow = Asrc + (size_t)(bm*128 + wid*32 + (lane>>3))*lda + c0 + (lane&7)*8;
    const unsigned short* brow = Bt   + (size_t)(bn*128 + wid*32 + (lane>>3))*K  + kt*64 + (lane&7)*8;
    #pragma unroll
    for (int i=0;i<4;i++){
      gld16(arow + (size_t)i*8*lda, &Al[(wid*32 + i*8)*64]);
      gld16(brow + (size_t)i*8*K,   &Bl[(wid*32 + i*8)*64]);
    }
    __syncthreads();
    #pragma unroll
    for (int ks=0; ks<2; ++ks){
      short8 a[4], b[4];
      #pragma unroll
      for (int m=0;m<4;m++)
        a[m] = *(const short8*)&Al[(wr*64 + m*16 + (lane&15))*64 + ks*32 + (lane>>4)*8];
      #pragma unroll
      for (int n=0;n<4;n++)
        b[n] = *(const short8*)&Bl[(wc*64 + n*16 + (lane&15))*64 + ks*32 + (lane>>4)*8];
      #pragma unroll
      for (int m=0;m<4;m++)
        #pragma unroll
        for (int n=0;n<4;n++)
          acc[m][n] = __builtin_amdgcn_mfma_f32_16x16x32_bf16(a[m], b[n], acc[m][n], 0, 0, 0);
    }
    __syncthreads();
  }

  #pragma unroll
  for (int m=0;m<4;m++){
    #pragma unroll
    for (int n=0;n<4;n++){
      #pragma unroll
      for (int j=0;j<4;j++){
        int row = bm*128 + wr*64 + m*16 + ((lane>>4)<<2) + j;
        int col = bn*128 + wc*64 + n*16 + (lane&15);
        if (row < M){
          float v = acc[m][n][j];
          if (BIAS) v += bias[col];
          if (RELU) v = fmaxf(v, 0.f);
          Cout[(size_t)row*ldC + col] = f2bf(v);
        }
      }
    }
  }
}

// ---------------- small prep kernels ----------------
__global__ void k_cvt(const float* __restrict__ in, unsigned short* __restrict__ out, int n4){
  int i = blockIdx.x*256 + threadIdx.x;
  if (i >= n4) return;
  float4 v = ((const float4*)in)[i];
  union { unsigned short u[4]; uint2 q; } t;
  t.u[0]=f2bf(v.x); t.u[1]=f2bf(v.y); t.u[2]=f2bf(v.z); t.u[3]=f2bf(v.w);
  ((uint2*)out)[i] = t.q;
}

// WT[(r*128+o)][i] = sum_b comp[r,b]*basis[b,i,o] ; coalesced reads + LDS transpose
// grid 256 blocks: r = bid>>4, i0 = (bid&15)*16
__global__ __launch_bounds__(256) void k_build_wt(const float* __restrict__ comp,
                                                  const float* __restrict__ basis,
                                                  unsigned short* __restrict__ WT){
  __shared__ float sm[16][129];
  __shared__ float cmp[NB_];
  int r = blockIdx.x >> 4, i0 = (blockIdx.x & 15)*16;
  int o = threadIdx.x & 127, ih = threadIdx.x >> 7;
  if (threadIdx.x < NB_) cmp[threadIdx.x] = comp[r*NB_ + threadIdx.x];
  __syncthreads();
  #pragma unroll
  for (int step=0; step<8; ++step){
    int i = i0 + step*2 + ih;
    float s = 0.f;
    #pragma unroll 6
    for (int b=0;b<NB_;b++) s += cmp[b]*basis[((size_t)b*FF + i)*HH + o];
    sm[step*2+ih][o] = s;
  }
  __syncthreads();
  #pragma unroll
  for (int w=0;w<8;w++){
    int o2 = w*16 + (threadIdx.x>>4);
    int ii = threadIdx.x & 15;
    WT[((size_t)(r*128 + o2))*FF + i0 + ii] = f2bf(sm[ii][o2]);
  }
}

// outT[o][k] = k<k0 ? in0[k*128+o] : in1[(k-k0)*128+o]    (bf16 B^T builder)
__global__ void k_transpose_cat(const float* __restrict__ in0, int k0,
                                const float* __restrict__ in1, int k1,
                                unsigned short* __restrict__ outT){
  int K = k0 + k1;
  int idx = blockIdx.x*256 + threadIdx.x;
  if (idx >= 128*K) return;
  int o = idx / K, k = idx % K;
  float v = (k < k0) ? in0[(size_t)k*HH + o] : in1[(size_t)(k-k0)*HH + o];
  outT[idx] = f2bf(v);
}

// ---------------- CSR by dst ----------------
__global__ void k_count(const int* __restrict__ dstv, int* __restrict__ counts){
  int e = blockIdx.x*256 + threadIdx.x;
  if (e >= EE) return;
  atomicAdd(&counts[dstv[e]], 1);
}

// hierarchical exclusive scan: 196 blocks x 256
__global__ __launch_bounds__(256) void k_scan1(const int* __restrict__ counts,
                                               int* __restrict__ row_ptr,
                                               int* __restrict__ blocksum){
  __shared__ int wsum[4];
  int g = blockIdx.x*256 + threadIdx.x;
  int lane = threadIdx.x & 63, wv = threadIdx.x >> 6;
  int v = (g < NN) ? counts[g] : 0;
  int s = v;
  #pragma unroll
  for (int off=1; off<64; off<<=1){ int t = __shfl_up(s, off, 64); if (lane>=off) s += t; }
  if (lane==63) wsum[wv] = s;
  __syncthreads();
  int wo = 0;
  #pragma unroll
  for (int i=0;i<4;i++) if (i < wv) wo += wsum[i];
  int incl = s + wo;
  if (g < NN) row_ptr[g] = incl - v;
  if (threadIdx.x == 255) blocksum[blockIdx.x] = incl;
}
__global__ __launch_bounds__(256) void k_scan2(int* __restrict__ blocksum, int nb){
  __shared__ int wsum[4];
  int t = threadIdx.x, lane = t & 63, wv = t >> 6;
  int v = (t < nb) ? blocksum[t] : 0;
  int s = v;
  #pragma unroll
  for (int off=1; off<64; off<<=1){ int u = __shfl_up(s, off, 64); if (lane>=off) s += u; }
  if (lane==63) wsum[wv] = s;
  __syncthreads();
  int wo = 0;
  #pragma unroll
  for (int i=0;i<4;i++) if (i < wv) wo += wsum[i];
  if (t < nb) blocksum[t] = s + wo - v;
}
__global__ __launch_bounds__(256) void k_scan3(int* __restrict__ row_ptr,
                                               const int* __restrict__ blocksum){
  int g = blockIdx.x*256 + threadIdx.x;
  if (g < NN) row_ptr[g] += blocksum[blockIdx.x];
  if (g == 0) row_ptr[NN] = EE;
}

__global__ void k_fill(const int* __restrict__ srcv, const int* __restrict__ dstv,
                       const int* __restrict__ etv, const int* __restrict__ row_ptr,
                       int* __restrict__ cursor, int* __restrict__ packed){
  int e = blockIdx.x*256 + threadIdx.x;
  if (e >= EE) return;
  int d = dstv[e];
  int p = atomicAdd(&cursor[d], 1);
  packed[row_ptr[d] + p] = (srcv[e] & 0xffff) | (etv[e] << 16);
}

// ---- RGCN aggregate: wave-per-node, uint loads (256B/wave/edge), 4-edge ILP ----
// out1 += mean-per-(dst,rel) messages; out1 pre-filled with x@root1+bias1.
__global__ __launch_bounds__(256) void k_agg1(const int* __restrict__ row_ptr,
                                              const int* __restrict__ packed,
                                              const unsigned int* __restrict__ xWu,
                                              unsigned int* __restrict__ out1u){
  __shared__ int   cnt[4][RR];
  __shared__ float inv[4][RR];
  const int lane = threadIdx.x & 63;
  const int wv   = threadIdx.x >> 6;
  const int node = blockIdx.x*4 + wv;          // grid exactly covers NN
  if (lane < RR) cnt[wv][lane] = 0;
  __syncthreads();
  const int b0 = row_ptr[node], b1 = row_ptr[node+1];
  for (int j=b0+lane; j<b1; j+=64) atomicAdd(&cnt[wv][(packed[j]>>16)&15], 1);
  __syncthreads();
  if (lane < RR) inv[wv][lane] = 1.0f / fmaxf((float)cnt[wv][lane], 1.0f);
  __syncthreads();

  float aA0=0.f, aA1=0.f, aB0=0.f, aB1=0.f;
  int j = b0;
  for (; j+4 <= b1; j+=4){
    int p0=packed[j], p1=packed[j+1], p2=packed[j+2], p3=packed[j+3];
    unsigned int v0 = xWu[((size_t)(((p0&0xffff)<<4)|((p0>>16)&15)) << 6) + lane];
    unsigned int v1 = xWu[((size_t)(((p1&0xffff)<<4)|((p1>>16)&15)) << 6) + lane];
    unsigned int v2 = xWu[((size_t)(((p2&0xffff)<<4)|((p2>>16)&15)) << 6) + lane];
    unsigned int v3 = xWu[((size_t)(((p3&0xffff)<<4)|((p3>>16)&15)) << 6) + lane];
    float i0=inv[wv][(p0>>16)&15], i1=inv[wv][(p1>>16)&15];
    float i2=inv[wv][(p2>>16)&15], i3=inv[wv][(p3>>16)&15];
    aA0 += bf2f((unsigned short)v0)*i0; aA1 += bf2f((unsigned short)(v0>>16))*i0;
    aB0 += bf2f((unsigned short)v1)*i1; aB1 += bf2f((unsigned short)(v1>>16))*i1;
    aA0 += bf2f((unsigned short)v2)*i2; aA1 += bf2f((unsigned short)(v2>>16))*i2;
    aB0 += bf2f((unsigned short)v3)*i3; aB1 += bf2f((unsigned short)(v3>>16))*i3;
  }
  for (; j<b1; ++j){
    int p = packed[j];
    unsigned int v = xWu[((size_t)(((p&0xffff)<<4)|((p>>16)&15)) << 6) + lane];
    float iv = inv[wv][(p>>16)&15];
    aA0 += bf2f((unsigned short)v)*iv; aA1 += bf2f((unsigned short)(v>>16))*iv;
  }
  size_t o = (size_t)node*64 + lane;
  unsigned int cur = out1u[o];
  float r0 = bf2f((unsigned short)cur)       + aA0 + aB0;
  float r1 = bf2f((unsigned short)(cur>>16)) + aA1 + aB1;
  out1u[o] = (unsigned int)f2bf(r0) | ((unsigned int)f2bf(r1) << 16);
}

// ---- GraphConv aggregate: wave-per-node, sum out1[src] ----
__global__ __launch_bounds__(256) void k_agg2(const int* __restrict__ row_ptr,
                                              const int* __restrict__ packed,
                                              const unsigned int* __restrict__ out1u,
                                              unsigned int* __restrict__ agg2u){
  const int lane = threadIdx.x & 63;
  const int wv   = threadIdx.x >> 6;
  const int node = blockIdx.x*4 + wv;
  const int b0 = row_ptr[node], b1 = row_ptr[node+1];
  float aA0=0.f, aA1=0.f, aB0=0.f, aB1=0.f;
  int j = b0;
  for (; j+4 <= b1; j+=4){
    int p0=packed[j]&0xffff, p1=packed[j+1]&0xffff, p2=packed[j+2]&0xffff, p3=packed[j+3]&0xffff;
    unsigned int v0 = out1u[(size_t)p0*64 + lane];
    unsigned int v1 = out1u[(size_t)p1*64 + lane];
    unsigned int v2 = out1u[(size_t)p2*64 + lane];
    unsigned int v3 = out1u[(size_t)p3*64 + lane];
    aA0 += bf2f((unsigned short)v0); aA1 += bf2f((unsigned short)(v0>>16));
    aB0 += bf2f((unsigned short)v1); aB1 += bf2f((unsigned short)(v1>>16));
    aA0 += bf2f((unsigned short)v2); aA1 += bf2f((unsigned short)(v2>>16));
    aB0 += bf2f((unsigned short)v3); aB1 += bf2f((unsigned short)(v3>>16));
  }
  for (; j<b1; ++j){
    unsigned int v = out1u[(size_t)(packed[j]&0xffff)*64 + lane];
    aA0 += bf2f((unsigned short)v); aA1 += bf2f((unsigned short)(v>>16));
  }
  agg2u[(size_t)node*64 + lane] = (unsigned int)f2bf(aA0+aB0) | ((unsigned int)f2bf(aA1+aB1) << 16);
}

// ---------------- head: logits + log_softmax ----------------
__global__ __launch_bounds__(256) void k_head(const unsigned short* __restrict__ hidden,
                                              const float* __restrict__ fc_w,
                                              const float* __restrict__ fc_b,
                                              float* __restrict__ out){
  int node = blockIdx.x*4 + (threadIdx.x >> 6);
  int lane = threadIdx.x & 63;
  if (node >= NN) return;
  float h0 = bf2f(hidden[(size_t)node*128 + lane*2]);
  float h1 = bf2f(hidden[(size_t)node*128 + lane*2 + 1]);
  float lg[CC];
  #pragma unroll
  for (int c=0;c<CC;c++){
    float p = h0*fc_w[(lane*2)*CC + c] + h1*fc_w[(lane*2+1)*CC + c];
    #pragma unroll
    for (int off=32; off; off>>=1) p += __shfl_down(p, off, 64);
    lg[c] = p;
  }
  if (lane == 0){
    float l[CC]; float m = -1e30f;
    #pragma unroll
    for (int c=0;c<CC;c++){ l[c] = lg[c] + fc_b[c]; m = fmaxf(m, l[c]); }
    float s = 0.f;
    #pragma unroll
    for (int c=0;c<CC;c++) s += expf(l[c]-m);
    float lse = logf(s);
    #pragma unroll
    for (int c=0;c<CC;c++) out[(size_t)node*CC + c] = l[c] - m - lse;
  }
}

extern "C" void kernel_launch(void* const* d_in, const int* in_sizes, int n_in,
                              void* d_out, int out_size, void* d_ws, size_t ws_size,
                              hipStream_t stream)
{
  const float* x      = (const float*)d_in[0];
  const int*   eidx   = (const int*)d_in[1];
  const int*   etype  = (const int*)d_in[3];
  const float* basis  = (const float*)d_in[8];
  const float* comp   = (const float*)d_in[9];
  const float* root1  = (const float*)d_in[10];
  const float* bias1  = (const float*)d_in[11];
  const float* w_rel  = (const float*)d_in[12];
  const float* w_root = (const float*)d_in[13];
  const float* bias2  = (const float*)d_in[14];
  const float* lin_w  = (const float*)d_in[15];
  const float* lin_b  = (const float*)d_in[16];
  const float* fc_w   = (const float*)d_in[17];
  const float* fc_b   = (const float*)d_in[18];
  const int* srcv = eidx;
  const int* dstv = eidx + EE;

  // workspace layout: total 248,316,416 B; A-source matrices padded to 50048 rows
  char* w = (char*)d_ws;
  unsigned short* x_bf    = (unsigned short*)(w + 0);                       // 50048*256*2
  unsigned short* xW      = (unsigned short*)(w + 25624576);                // 50000*2048*2 (dead after k_agg1)
  unsigned short* hidden  = (unsigned short*)(w + 25624576);                //  alias
  unsigned short* out2_bf = (unsigned short*)(w + 25624576 + 12812288);     //  alias (padded)
  unsigned short* agg2_bf = (unsigned short*)(w + 25624576 + 25624576);     //  alias (padded)
  unsigned short* WT      = (unsigned short*)(w + 230424576);               // 1,048,576
  unsigned short* rootT   = (unsigned short*)(w + 231473152);               // 65,536
  unsigned short* W2T     = (unsigned short*)(w + 231538688);               // 65,536
  unsigned short* linT    = (unsigned short*)(w + 231604224);               // 98,304
  unsigned short* out1_bf = (unsigned short*)(w + 231702528);               // 50048*128*2 (padded)
  int*            counts  = (int*)(w + 244514816);                          // 200,192
  int*            row_ptr = (int*)(w + 244715008);                          // 200,192
  int*            cursor  = (int*)(w + 244915200);                          // 200,192
  int*            packed  = (int*)(w + 245115392);                          // 3,200,000
  int*            blocksum= (int*)(w + 248315392);                          // 1,024

  hipMemsetAsync(counts, 0, NN*4, stream);
  hipMemsetAsync(cursor, 0, NN*4, stream);

  // prep
  k_cvt<<<12500, 256, 0, stream>>>(x, x_bf, NN*FF/4);
  k_build_wt<<<256, 256, 0, stream>>>(comp, basis, WT);
  k_transpose_cat<<<128, 256, 0, stream>>>(root1, 256, nullptr, 0, rootT);
  k_transpose_cat<<<128, 256, 0, stream>>>(w_rel, 128, w_root, 128, W2T);
  k_transpose_cat<<<192, 256, 0, stream>>>(lin_w, 384, nullptr, 0, linT);

  // CSR by dst
  k_count<<<3125, 256, 0, stream>>>(dstv, counts);
  k_scan1<<<196, 256, 0, stream>>>(counts, row_ptr, blocksum);
  k_scan2<<<1, 256, 0, stream>>>(blocksum, 196);
  k_scan3<<<196, 256, 0, stream>>>(row_ptr, blocksum);
  k_fill<<<3125, 256, 0, stream>>>(srcv, dstv, etype, row_ptr, cursor, packed);

  // GEMM1: xW = x_bf @ W  -> [N, 2048] bf16
  {
    dim3 g(391, 16);
    gemm_bt<false,false><<<g, 256, 0, stream>>>(
        x_bf, FF, nullptr, 0, 1<<30, WT, xW, 2048, nullptr, NN, FF);
  }
  // root: out1_bf = x_bf @ root1 + bias1  (bf16)
  {
    dim3 g(391, 1);
    gemm_bt<true,false><<<g, 256, 0, stream>>>(
        x_bf, FF, nullptr, 0, 1<<30, rootT, out1_bf, HH, bias1, NN, FF);
  }
  // RGCN aggregate: out1_bf += mean-per-(dst,rel) messages
  k_agg1<<<12500, 256, 0, stream>>>(row_ptr, packed, (const unsigned int*)xW, (unsigned int*)out1_bf);
  // GraphConv aggregate -> agg2_bf
  k_agg2<<<12500, 256, 0, stream>>>(row_ptr, packed, (const unsigned int*)out1_bf, (unsigned int*)agg2_bf);
  // GEMM2: out2 = [agg2 | out1] @ [w_rel; w_root] + bias2 -> bf16
  {
    dim3 g(391, 1);
    gemm_bt<true,false><<<g, 256, 0, stream>>>(
        agg2_bf, HH, out1_bf, HH, HH, W2T, out2_bf, HH, bias2, NN, 2*HH);
  }
  // GEMM3: hidden = relu([x | out2] @ lin_w + lin_b) -> bf16
  {
    dim3 g(391, 1);
    gemm_bt<true,true><<<g, 256, 0, stream>>>(
        x_bf, FF, out2_bf, HH, FF, linT, hidden, HH, lin_b, NN, FF+HH);
  }
  // head
  k_head<<<12500, 256, 0, stream>>>(hidden, fc_w, fc_b, (float*)d_out);
}

// Round 5
// 408.588 us; speedup vs baseline: 1.8235x; 1.0315x over previous
//
#include <hip/hip_runtime.h>
#include <hip/hip_bf16.h>
#include <stdint.h>

#define NN 50000
#define FF 256
#define HH 128
#define RR 16
#define EE 800000
#define CC 7
#define NB_ 30

typedef __attribute__((ext_vector_type(8))) short short8;
typedef __attribute__((ext_vector_type(4))) float f32x4;

__device__ __forceinline__ float bf2f(unsigned short u){
  union { unsigned int i; float f; } x; x.i = ((unsigned int)u) << 16; return x.f;
}
__device__ __forceinline__ unsigned short f2bf(float f){
  union { unsigned int i; float f; } x; x.f = f;
  unsigned int r = x.i + 0x7fffu + ((x.i >> 16) & 1u);
  return (unsigned short)(r >> 16);
}

__device__ __forceinline__ void gld16(const unsigned short* g, unsigned short* l){
  __builtin_amdgcn_global_load_lds(
      (const __attribute__((address_space(1))) unsigned int*)g,
      (__attribute__((address_space(3))) unsigned int*)l, 16, 0, 0);
}

// ---------------- bf16 MFMA GEMM: C[M,Ncols] = A[M,K] * Bt[Ncols,K]^T ----------
// m97 structure: 128x128 tile, BK=64, 4 waves, global_load_lds staging, linear LDS.
// Swapped-operand MFMA (acc holds C^T fragment) -> each lane owns 4 consecutive
// output cols -> packed 8B stores. RASTER: 1D grid, XCD-chunked 8x16 panels.
template<bool BIAS, bool RELU, bool RASTER>
__global__ __launch_bounds__(256) void gemm_bt(
    const unsigned short* __restrict__ A0, int ldA0,
    const unsigned short* __restrict__ A1, int ldA1, int kSplit,
    const unsigned short* __restrict__ Bt,
    unsigned short* __restrict__ Cout, int ldC,
    const float* __restrict__ bias,
    int M, int K)
{
  __shared__ unsigned short Al[128*64];
  __shared__ unsigned short Bl[128*64];
  const int tid  = threadIdx.x;
  const int lane = tid & 63;
  const int wid  = tid >> 6;
  const int wr   = wid >> 1, wc = wid & 1;
  int bm, bn;
  if (RASTER){
    // 6256 blocks = 8 XCD chunks x 782; panels of 8 bm x 16 bn (128 blocks)
    int idx  = blockIdx.x;
    int cidx = (idx & 7)*782 + (idx >> 3);
    int p = cidx >> 7;
    int within = cidx & 127;
    int ph = min(8, 391 - p*8);
    bn = within / ph;
    bm = p*8 + within % ph;
  } else {
    bm = blockIdx.x; bn = blockIdx.y;
  }

  f32x4 acc[4][4];
  #pragma unroll
  for (int m=0;m<4;m++)
    #pragma unroll
    for (int n=0;n<4;n++) acc[m][n] = (f32x4){0.f,0.f,0.f,0.f};

  const int nkt = K >> 6;
  for (int kt=0; kt<nkt; ++kt){
    int c0 = kt*64;
    const unsigned short* Asrc = A0; int lda = ldA0;
    if (c0 >= kSplit){ Asrc = A1; lda = ldA1; c0 -= kSplit; }
    // stage: each wave loads 32 rows of A and 32 rows of B (4 x 1KB each)
    const unsigned short* arow = Asrc + (size_t)(bm*128 + wid*32 + (lane>>3))*lda + c0 + (lane&7)*8;
    const unsigned short* brow = Bt   + (size_t)(bn*128 + wid*32 + (lane>>3))*K  + kt*64 + (lane&7)*8;
    #pragma unroll
    for (int i=0;i<4;i++){
      gld16(arow + (size_t)i*8*lda, &Al[(wid*32 + i*8)*64]);
      gld16(brow + (size_t)i*8*K,   &Bl[(wid*32 + i*8)*64]);
    }
    __syncthreads();
    #pragma unroll
    for (int ks=0; ks<2; ++ks){
      short8 a[4], b[4];
      #pragma unroll
      for (int m=0;m<4;m++)
        a[m] = *(const short8*)&Al[(wr*64 + m*16 + (lane&15))*64 + ks*32 + (lane>>4)*8];
      #pragma unroll
      for (int n=0;n<4;n++)
        b[n] = *(const short8*)&Bl[(wc*64 + n*16 + (lane&15))*64 + ks*32 + (lane>>4)*8];
      // swapped operands: acc = (A.B^T)^T fragment
      #pragma unroll
      for (int m=0;m<4;m++)
        #pragma unroll
        for (int n=0;n<4;n++)
          acc[m][n] = __builtin_amdgcn_mfma_f32_16x16x32_bf16(b[n], a[m], acc[m][n], 0, 0, 0);
    }
    __syncthreads();
  }

  // epilogue: row = lane&15, cols = (lane>>4)*4 + j  -> one 8B store per (m,n)
  #pragma unroll
  for (int m=0;m<4;m++){
    int row = bm*128 + wr*64 + m*16 + (lane&15);
    if (row < M){
      #pragma unroll
      for (int n=0;n<4;n++){
        int col = bn*128 + wc*64 + n*16 + ((lane>>4)<<2);
        float v0 = acc[m][n][0], v1 = acc[m][n][1], v2 = acc[m][n][2], v3 = acc[m][n][3];
        if (BIAS){ v0 += bias[col]; v1 += bias[col+1]; v2 += bias[col+2]; v3 += bias[col+3]; }
        if (RELU){ v0 = fmaxf(v0,0.f); v1 = fmaxf(v1,0.f); v2 = fmaxf(v2,0.f); v3 = fmaxf(v3,0.f); }
        unsigned int lo = (unsigned int)f2bf(v0) | ((unsigned int)f2bf(v1) << 16);
        unsigned int hi = (unsigned int)f2bf(v2) | ((unsigned int)f2bf(v3) << 16);
        *(uint2*)&Cout[(size_t)row*ldC + col] = make_uint2(lo, hi);
      }
    }
  }
}

// ---------------- small prep kernels ----------------
__global__ void k_cvt(const float* __restrict__ in, unsigned short* __restrict__ out, int n4){
  int i = blockIdx.x*256 + threadIdx.x;
  if (i >= n4) return;
  float4 v = ((const float4*)in)[i];
  union { unsigned short u[4]; uint2 q; } t;
  t.u[0]=f2bf(v.x); t.u[1]=f2bf(v.y); t.u[2]=f2bf(v.z); t.u[3]=f2bf(v.w);
  ((uint2*)out)[i] = t.q;
}

// WT[(r*128+o)][i] = sum_b comp[r,b]*basis[b,i,o] ; coalesced reads + LDS transpose
__global__ __launch_bounds__(256) void k_build_wt(const float* __restrict__ comp,
                                                  const float* __restrict__ basis,
                                                  unsigned short* __restrict__ WT){
  __shared__ float sm[16][129];
  __shared__ float cmp[NB_];
  int r = blockIdx.x >> 4, i0 = (blockIdx.x & 15)*16;
  int o = threadIdx.x & 127, ih = threadIdx.x >> 7;
  if (threadIdx.x < NB_) cmp[threadIdx.x] = comp[r*NB_ + threadIdx.x];
  __syncthreads();
  #pragma unroll
  for (int step=0; step<8; ++step){
    int i = i0 + step*2 + ih;
    float s = 0.f;
    #pragma unroll 6
    for (int b=0;b<NB_;b++) s += cmp[b]*basis[((size_t)b*FF + i)*HH + o];
    sm[step*2+ih][o] = s;
  }
  __syncthreads();
  #pragma unroll
  for (int w=0;w<8;w++){
    int o2 = w*16 + (threadIdx.x>>4);
    int ii = threadIdx.x & 15;
    WT[((size_t)(r*128 + o2))*FF + i0 + ii] = f2bf(sm[ii][o2]);
  }
}

// outT[o][k] = k<k0 ? in0[k*128+o] : in1[(k-k0)*128+o]    (bf16 B^T builder)
__global__ void k_transpose_cat(const float* __restrict__ in0, int k0,
                                const float* __restrict__ in1, int k1,
                                unsigned short* __restrict__ outT){
  int K = k0 + k1;
  int idx = blockIdx.x*256 + threadIdx.x;
  if (idx >= 128*K) return;
  int o = idx / K, k = idx % K;
  float v = (k < k0) ? in0[(size_t)k*HH + o] : in1[(size_t)(k-k0)*HH + o];
  outT[idx] = f2bf(v);
}

// ---------------- CSR by dst ----------------
__global__ void k_count(const int* __restrict__ dstv, int* __restrict__ counts){
  int e = blockIdx.x*256 + threadIdx.x;
  if (e >= EE) return;
  atomicAdd(&counts[dstv[e]], 1);
}

// hierarchical exclusive scan: 196 blocks x 256
__global__ __launch_bounds__(256) void k_scan1(const int* __restrict__ counts,
                                               int* __restrict__ row_ptr,
                                               int* __restrict__ blocksum){
  __shared__ int wsum[4];
  int g = blockIdx.x*256 + threadIdx.x;
  int lane = threadIdx.x & 63, wv = threadIdx.x >> 6;
  int v = (g < NN) ? counts[g] : 0;
  int s = v;
  #pragma unroll
  for (int off=1; off<64; off<<=1){ int t = __shfl_up(s, off, 64); if (lane>=off) s += t; }
  if (lane==63) wsum[wv] = s;
  __syncthreads();
  int wo = 0;
  #pragma unroll
  for (int i=0;i<4;i++) if (i < wv) wo += wsum[i];
  int incl = s + wo;
  if (g < NN) row_ptr[g] = incl - v;
  if (threadIdx.x == 255) blocksum[blockIdx.x] = incl;
}
__global__ __launch_bounds__(256) void k_scan2(int* __restrict__ blocksum, int nb){
  __shared__ int wsum[4];
  int t = threadIdx.x, lane = t & 63, wv = t >> 6;
  int v = (t < nb) ? blocksum[t] : 0;
  int s = v;
  #pragma unroll
  for (int off=1; off<64; off<<=1){ int u = __shfl_up(s, off, 64); if (lane>=off) s += u; }
  if (lane==63) wsum[wv] = s;
  __syncthreads();
  int wo = 0;
  #pragma unroll
  for (int i=0;i<4;i++) if (i < wv) wo += wsum[i];
  if (t < nb) blocksum[t] = s + wo - v;
}
__global__ __launch_bounds__(256) void k_scan3(int* __restrict__ row_ptr,
                                               const int* __restrict__ blocksum){
  int g = blockIdx.x*256 + threadIdx.x;
  if (g < NN) row_ptr[g] += blocksum[blockIdx.x];
  if (g == 0) row_ptr[NN] = EE;
}

__global__ void k_fill(const int* __restrict__ srcv, const int* __restrict__ dstv,
                       const int* __restrict__ etv, const int* __restrict__ row_ptr,
                       int* __restrict__ cursor, int* __restrict__ packed){
  int e = blockIdx.x*256 + threadIdx.x;
  if (e >= EE) return;
  int d = dstv[e];
  int p = atomicAdd(&cursor[d], 1);
  packed[row_ptr[d] + p] = (srcv[e] & 0xffff) | (etv[e] << 16);
}

// ---- RGCN aggregate: wave-per-node, uint loads (256B/wave/edge), 8-edge ILP ----
__global__ __launch_bounds__(256) void k_agg1(const int* __restrict__ row_ptr,
                                              const int* __restrict__ packed,
                                              const unsigned int* __restrict__ xWu,
                                              unsigned int* __restrict__ out1u){
  __shared__ int   cnt[4][RR];
  __shared__ float inv[4][RR];
  const int lane = threadIdx.x & 63;
  const int wv   = threadIdx.x >> 6;
  const int node = blockIdx.x*4 + wv;          // grid exactly covers NN
  if (lane < RR) cnt[wv][lane] = 0;
  __syncthreads();
  const int b0 = row_ptr[node], b1 = row_ptr[node+1];
  for (int j=b0+lane; j<b1; j+=64) atomicAdd(&cnt[wv][(packed[j]>>16)&15], 1);
  __syncthreads();
  if (lane < RR) inv[wv][lane] = 1.0f / fmaxf((float)cnt[wv][lane], 1.0f);
  __syncthreads();

  float a0=0.f, a1=0.f;
  int j = b0;
  for (; j+8 <= b1; j+=8){
    int pv[8]; unsigned int vv[8];
    #pragma unroll
    for (int q=0;q<8;q++) pv[q] = packed[j+q];
    #pragma unroll
    for (int q=0;q<8;q++)
      vv[q] = xWu[((size_t)(((pv[q]&0xffff)<<4)|((pv[q]>>16)&15)) << 6) + lane];
    #pragma unroll
    for (int q=0;q<8;q++){
      float f = inv[wv][(pv[q]>>16)&15];
      a0 += bf2f((unsigned short)vv[q])*f;
      a1 += bf2f((unsigned short)(vv[q]>>16))*f;
    }
  }
  for (; j+4 <= b1; j+=4){
    int pv[4]; unsigned int vv[4];
    #pragma unroll
    for (int q=0;q<4;q++) pv[q] = packed[j+q];
    #pragma unroll
    for (int q=0;q<4;q++)
      vv[q] = xWu[((size_t)(((pv[q]&0xffff)<<4)|((pv[q]>>16)&15)) << 6) + lane];
    #pragma unroll
    for (int q=0;q<4;q++){
      float f = inv[wv][(pv[q]>>16)&15];
      a0 += bf2f((unsigned short)vv[q])*f;
      a1 += bf2f((unsigned short)(vv[q]>>16))*f;
    }
  }
  for (; j<b1; ++j){
    int p = packed[j];
    unsigned int v = xWu[((size_t)(((p&0xffff)<<4)|((p>>16)&15)) << 6) + lane];
    float f = inv[wv][(p>>16)&15];
    a0 += bf2f((unsigned short)v)*f;
    a1 += bf2f((unsigned short)(v>>16))*f;
  }
  size_t o = (size_t)node*64 + lane;
  unsigned int cur = out1u[o];
  float r0 = bf2f((unsigned short)cur)       + a0;
  float r1 = bf2f((unsigned short)(cur>>16)) + a1;
  out1u[o] = (unsigned int)f2bf(r0) | ((unsigned int)f2bf(r1) << 16);
}

// ---- GraphConv aggregate: wave-per-node, sum out1[src], 8-edge ILP ----
__global__ __launch_bounds__(256) void k_agg2(const int* __restrict__ row_ptr,
                                              const int* __restrict__ packed,
                                              const unsigned int* __restrict__ out1u,
                                              unsigned int* __restrict__ agg2u){
  const int lane = threadIdx.x & 63;
  const int wv   = threadIdx.x >> 6;
  const int node = blockIdx.x*4 + wv;
  const int b0 = row_ptr[node], b1 = row_ptr[node+1];
  float a0=0.f, a1=0.f;
  int j = b0;
  for (; j+8 <= b1; j+=8){
    unsigned int vv[8];
    #pragma unroll
    for (int q=0;q<8;q++)
      vv[q] = out1u[(size_t)(packed[j+q]&0xffff)*64 + lane];
    #pragma unroll
    for (int q=0;q<8;q++){
      a0 += bf2f((unsigned short)vv[q]);
      a1 += bf2f((unsigned short)(vv[q]>>16));
    }
  }
  for (; j+4 <= b1; j+=4){
    unsigned int vv[4];
    #pragma unroll
    for (int q=0;q<4;q++)
      vv[q] = out1u[(size_t)(packed[j+q]&0xffff)*64 + lane];
    #pragma unroll
    for (int q=0;q<4;q++){
      a0 += bf2f((unsigned short)vv[q]);
      a1 += bf2f((unsigned short)(vv[q]>>16));
    }
  }
  for (; j<b1; ++j){
    unsigned int v = out1u[(size_t)(packed[j]&0xffff)*64 + lane];
    a0 += bf2f((unsigned short)v);
    a1 += bf2f((unsigned short)(v>>16));
  }
  agg2u[(size_t)node*64 + lane] = (unsigned int)f2bf(a0) | ((unsigned int)f2bf(a1) << 16);
}

// ---------------- head: logits + log_softmax ----------------
__global__ __launch_bounds__(256) void k_head(const unsigned short* __restrict__ hidden,
                                              const float* __restrict__ fc_w,
                                              const float* __restrict__ fc_b,
                                              float* __restrict__ out){
  int node = blockIdx.x*4 + (threadIdx.x >> 6);
  int lane = threadIdx.x & 63;
  if (node >= NN) return;
  float h0 = bf2f(hidden[(size_t)node*128 + lane*2]);
  float h1 = bf2f(hidden[(size_t)node*128 + lane*2 + 1]);
  float lg[CC];
  #pragma unroll
  for (int c=0;c<CC;c++){
    float p = h0*fc_w[(lane*2)*CC + c] + h1*fc_w[(lane*2+1)*CC + c];
    #pragma unroll
    for (int off=32; off; off>>=1) p += __shfl_down(p, off, 64);
    lg[c] = p;
  }
  if (lane == 0){
    float l[CC]; float m = -1e30f;
    #pragma unroll
    for (int c=0;c<CC;c++){ l[c] = lg[c] + fc_b[c]; m = fmaxf(m, l[c]); }
    float s = 0.f;
    #pragma unroll
    for (int c=0;c<CC;c++) s += expf(l[c]-m);
    float lse = logf(s);
    #pragma unroll
    for (int c=0;c<CC;c++) out[(size_t)node*CC + c] = l[c] - m - lse;
  }
}

extern "C" void kernel_launch(void* const* d_in, const int* in_sizes, int n_in,
                              void* d_out, int out_size, void* d_ws, size_t ws_size,
                              hipStream_t stream)
{
  const float* x      = (const float*)d_in[0];
  const int*   eidx   = (const int*)d_in[1];
  const int*   etype  = (const int*)d_in[3];
  const float* basis  = (const float*)d_in[8];
  const float* comp   = (const float*)d_in[9];
  const float* root1  = (const float*)d_in[10];
  const float* bias1  = (const float*)d_in[11];
  const float* w_rel  = (const float*)d_in[12];
  const float* w_root = (const float*)d_in[13];
  const float* bias2  = (const float*)d_in[14];
  const float* lin_w  = (const float*)d_in[15];
  const float* lin_b  = (const float*)d_in[16];
  const float* fc_w   = (const float*)d_in[17];
  const float* fc_b   = (const float*)d_in[18];
  const int* srcv = eidx;
  const int* dstv = eidx + EE;

  // workspace layout: total 248,316,416 B; A-source matrices padded to 50048 rows
  char* w = (char*)d_ws;
  unsigned short* x_bf    = (unsigned short*)(w + 0);                       // 50048*256*2
  unsigned short* xW      = (unsigned short*)(w + 25624576);                // 50000*2048*2 (dead after k_agg1)
  unsigned short* hidden  = (unsigned short*)(w + 25624576);                //  alias
  unsigned short* out2_bf = (unsigned short*)(w + 25624576 + 12812288);     //  alias (padded)
  unsigned short* agg2_bf = (unsigned short*)(w + 25624576 + 25624576);     //  alias (padded)
  unsigned short* WT      = (unsigned short*)(w + 230424576);               // 1,048,576
  unsigned short* rootT   = (unsigned short*)(w + 231473152);               // 65,536
  unsigned short* W2T     = (unsigned short*)(w + 231538688);               // 65,536
  unsigned short* linT    = (unsigned short*)(w + 231604224);               // 98,304
  unsigned short* out1_bf = (unsigned short*)(w + 231702528);               // 50048*128*2 (padded)
  int*            counts  = (int*)(w + 244514816);                          // 200,192
  int*            row_ptr = (int*)(w + 244715008);                          // 200,192
  int*            cursor  = (int*)(w + 244915200);                          // 200,192
  int*            packed  = (int*)(w + 245115392);                          // 3,200,000
  int*            blocksum= (int*)(w + 248315392);                          // 1,024

  hipMemsetAsync(counts, 0, NN*4, stream);
  hipMemsetAsync(cursor, 0, NN*4, stream);

  // prep
  k_cvt<<<12500, 256, 0, stream>>>(x, x_bf, NN*FF/4);
  k_build_wt<<<256, 256, 0, stream>>>(comp, basis, WT);
  k_transpose_cat<<<128, 256, 0, stream>>>(root1, 256, nullptr, 0, rootT);
  k_transpose_cat<<<128, 256, 0, stream>>>(w_rel, 128, w_root, 128, W2T);
  k_transpose_cat<<<192, 256, 0, stream>>>(lin_w, 384, nullptr, 0, linT);

  // CSR by dst
  k_count<<<3125, 256, 0, stream>>>(dstv, counts);
  k_scan1<<<196, 256, 0, stream>>>(counts, row_ptr, blocksum);
  k_scan2<<<1, 256, 0, stream>>>(blocksum, 196);
  k_scan3<<<196, 256, 0, stream>>>(row_ptr, blocksum);
  k_fill<<<3125, 256, 0, stream>>>(srcv, dstv, etype, row_ptr, cursor, packed);

  // GEMM1: xW = x_bf @ W  -> [N, 2048] bf16   (rasterized 1D grid: 391*16 = 6256)
  gemm_bt<false,false,true><<<6256, 256, 0, stream>>>(
      x_bf, FF, nullptr, 0, 1<<30, WT, xW, 2048, nullptr, NN, FF);
  // root: out1_bf = x_bf @ root1 + bias1  (bf16)
  {
    dim3 g(391, 1);
    gemm_bt<true,false,false><<<g, 256, 0, stream>>>(
        x_bf, FF, nullptr, 0, 1<<30, rootT, out1_bf, HH, bias1, NN, FF);
  }
  // RGCN aggregate: out1_bf += mean-per-(dst,rel) messages
  k_agg1<<<12500, 256, 0, stream>>>(row_ptr, packed, (const unsigned int*)xW, (unsigned int*)out1_bf);
  // GraphConv aggregate -> agg2_bf
  k_agg2<<<12500, 256, 0, stream>>>(row_ptr, packed, (const unsigned int*)out1_bf, (unsigned int*)agg2_bf);
  // GEMM2: out2 = [agg2 | out1] @ [w_rel; w_root] + bias2 -> bf16
  {
    dim3 g(391, 1);
    gemm_bt<true,false,false><<<g, 256, 0, stream>>>(
        agg2_bf, HH, out1_bf, HH, HH, W2T, out2_bf, HH, bias2, NN, 2*HH);
  }
  // GEMM3: hidden = relu([x | out2] @ lin_w + lin_b) -> bf16
  {
    dim3 g(391, 1);
    gemm_bt<true,true,false><<<g, 256, 0, stream>>>(
        x_bf, FF, out2_bf, HH, FF, linT, hidden, HH, lin_b, NN, FF+HH);
  }
  // head
  k_head<<<12500, 256, 0, stream>>>(hidden, fc_w, fc_b, (float*)d_out);
}